// Round 1
// baseline (10525.028 us; speedup 1.0000x reference)
//
#include <hip/hip_runtime.h>

// GCN: N=100000 nodes, E=3200000 edges, dims 8 -> 64 -> 64 -> 112
// out[i] = dinv[i] * (th[i] + sum_{j->i} th[j]) + b,  th[j] = (h[j] @ W) * dinv[j]
// deg[i] = indeg(i) + 1 (self-loop), dinv = rsqrt(deg)

#define NNODES 100000
#define NEDGES 3200000

__global__ void deg_init_kernel(float* __restrict__ deg) {
    int i = blockIdx.x * blockDim.x + threadIdx.x;
    if (i < NNODES) deg[i] = 1.0f;  // self-loop contribution
}

__global__ void deg_edge_kernel(const int* __restrict__ dst, float* __restrict__ deg) {
    int e = blockIdx.x * blockDim.x + threadIdx.x;
    if (e < NEDGES) atomicAdd(&deg[dst[e]], 1.0f);
}

__global__ void deg_rsqrt_kernel(float* __restrict__ deg) {
    int i = blockIdx.x * blockDim.x + threadIdx.x;
    if (i < NNODES) deg[i] = rsqrtf(deg[i]);  // deg >= 1 always
}

// th[i][f] = (in[i][:] @ W[:][f]) * dinv[i];  also initializes acc = th (self-loop term)
template<int FIN, int FOUT>
__global__ void transform_kernel(const float* __restrict__ in, const float* __restrict__ W,
                                 const float* __restrict__ dinv,
                                 float* __restrict__ th, float* __restrict__ acc) {
    __shared__ float Ws[FIN * FOUT];
    for (int t = threadIdx.x; t < FIN * FOUT; t += blockDim.x) Ws[t] = W[t];
    __syncthreads();

    int idx = blockIdx.x * blockDim.x + threadIdx.x;  // N*FOUT <= 11.2M, fits int
    if (idx >= NNODES * FOUT) return;
    int i = idx / FOUT;  // FOUT is compile-time -> magic multiply
    int f = idx % FOUT;

    const float* row = in + i * FIN;
    float sum = 0.f;
#pragma unroll
    for (int k = 0; k < FIN; ++k) sum += row[k] * Ws[k * FOUT + f];

    float v = sum * dinv[i];
    th[idx]  = v;
    acc[idx] = v;
}

// Edge-parallel scatter: 16 lanes per edge, float4-granular gather + 4x f32 atomicAdd.
template<int FOUT>
__global__ void scatter_kernel(const int* __restrict__ src, const int* __restrict__ dst,
                               const float* __restrict__ th, float* __restrict__ acc) {
    int tid = blockIdx.x * blockDim.x + threadIdx.x;
    int e  = tid >> 4;
    int lg = tid & 15;
    if (e >= NEDGES) return;
    int s = src[e];
    int d = dst[e];
    const float4* trow = (const float4*)(th + s * FOUT);
    float* arow = acc + d * FOUT;
    constexpr int NQ = FOUT / 4;  // 16 (F=64) or 28 (F=112)
#pragma unroll
    for (int j = lg; j < NQ; j += 16) {
        float4 v = trow[j];
        atomicAdd(arow + 4 * j + 0, v.x);
        atomicAdd(arow + 4 * j + 1, v.y);
        atomicAdd(arow + 4 * j + 2, v.z);
        atomicAdd(arow + 4 * j + 3, v.w);
    }
}

// out[i][f] = maybe_relu(acc[i][f] * dinv[i] + b[f])
template<int FOUT, bool RELU>
__global__ void finish_kernel(const float* __restrict__ acc, const float* __restrict__ dinv,
                              const float* __restrict__ b, float* __restrict__ out) {
    int idx = blockIdx.x * blockDim.x + threadIdx.x;
    if (idx >= NNODES * FOUT) return;
    int i = idx / FOUT;
    int f = idx % FOUT;
    float v = acc[idx] * dinv[i] + b[f];
    if (RELU) v = fmaxf(v, 0.f);
    out[idx] = v;
}

extern "C" void kernel_launch(void* const* d_in, const int* in_sizes, int n_in,
                              void* d_out, int out_size, void* d_ws, size_t ws_size,
                              hipStream_t stream) {
    const float* x  = (const float*)d_in[0];
    const int*   ei = (const int*)d_in[1];     // int32 (jax x64 disabled)
    const float* W1 = (const float*)d_in[2];
    const float* b1 = (const float*)d_in[3];
    const float* W2 = (const float*)d_in[4];
    const float* b2 = (const float*)d_in[5];
    const float* W3 = (const float*)d_in[6];
    const float* b3 = (const float*)d_in[7];

    const int* src = ei;            // edge_index[0]
    const int* dst = ei + NEDGES;   // edge_index[1]

    float* out  = (float*)d_out;                    // N*112
    float* dinv = (float*)d_ws;                     // N floats
    float* bufA = dinv + 131072;                    // N*112 floats
    float* bufB = bufA + NNODES * 112;              // N*112 floats
    // total ws use: ~90 MB

    const int B = 256;
    int gN    = (NNODES + B - 1) / B;
    int gE    = (NEDGES + B - 1) / B;
    int gN64  = (NNODES * 64 + B - 1) / B;
    int gN112 = (NNODES * 112 + B - 1) / B;
    int gScat = (NEDGES * 16) / B;   // 200000 blocks

    // --- degree / normalization ---
    deg_init_kernel<<<gN, B, 0, stream>>>(dinv);
    deg_edge_kernel<<<gE, B, 0, stream>>>(dst, dinv);
    deg_rsqrt_kernel<<<gN, B, 0, stream>>>(dinv);

    // --- layer 1: x(8) -> 64, ReLU ---
    transform_kernel<8, 64><<<gN64, B, 0, stream>>>(x, W1, dinv, bufA, bufB);
    scatter_kernel<64><<<gScat, B, 0, stream>>>(src, dst, bufA, bufB);
    finish_kernel<64, true><<<gN64, B, 0, stream>>>(bufB, dinv, b1, bufA);

    // --- layer 2: 64 -> 64, ReLU (acc lives in d_out as scratch) ---
    transform_kernel<64, 64><<<gN64, B, 0, stream>>>(bufA, W2, dinv, bufB, out);
    scatter_kernel<64><<<gScat, B, 0, stream>>>(src, dst, bufB, out);
    finish_kernel<64, true><<<gN64, B, 0, stream>>>(out, dinv, b2, bufA);

    // --- layer 3: 64 -> 112, no ReLU ---
    transform_kernel<64, 112><<<gN112, B, 0, stream>>>(bufA, W3, dinv, bufB, out);
    scatter_kernel<112><<<gScat, B, 0, stream>>>(src, dst, bufB, out);
    finish_kernel<112, false><<<gN112, B, 0, stream>>>(out, dinv, b3, out);
}

// Round 2
// 1315.827 us; speedup vs baseline: 7.9988x; 7.9988x over previous
//
#include <hip/hip_runtime.h>

// GCN: N=100000 nodes, E=3200000 edges, dims 8 -> 64 -> 64 -> 112
// out[i] = dinv[i] * (th[i] + sum_{j->i} th[j]) + b,  th[j] = (h[j] @ W) * dinv[j]
// deg[i] = indeg(i) + 1 (self-loop), dinv = rsqrt(deg)
//
// Strategy: build CSR by dst (int histogram + scan + cursor fill), then
// node-parallel register gather (no float atomics). Epilogue fused into gather.

#define NNODES 100000
#define NEDGES 3200000
#define NBLK   ((NNODES + 255) / 256)   // 391 scan blocks

// ---------------- CSR build ----------------

__global__ void cnt_init_kernel(int* __restrict__ cnt) {
    int i = blockIdx.x * blockDim.x + threadIdx.x;
    if (i < NNODES) cnt[i] = 0;
}

__global__ void hist_kernel(const int* __restrict__ dst, int* __restrict__ cnt) {
    int e = blockIdx.x * blockDim.x + threadIdx.x;
    if (e < NEDGES) atomicAdd(&cnt[dst[e]], 1);
}

// per-block exclusive scan; block sums out
__global__ void scan1_kernel(const int* __restrict__ cnt, int* __restrict__ excl,
                             int* __restrict__ bsum) {
    __shared__ int sh[256];
    int i = blockIdx.x * 256 + threadIdx.x;
    int v = (i < NNODES) ? cnt[i] : 0;
    sh[threadIdx.x] = v;
    __syncthreads();
    for (int off = 1; off < 256; off <<= 1) {
        int t = (threadIdx.x >= off) ? sh[threadIdx.x - off] : 0;
        __syncthreads();
        sh[threadIdx.x] += t;
        __syncthreads();
    }
    if (i < NNODES) excl[i] = sh[threadIdx.x] - v;   // exclusive
    if (threadIdx.x == 255) bsum[blockIdx.x] = sh[255];
}

// single-block exclusive scan of the 391 block sums
__global__ void scan2_kernel(int* __restrict__ bsum) {
    __shared__ int sh[512];
    int v = (threadIdx.x < NBLK) ? bsum[threadIdx.x] : 0;
    sh[threadIdx.x] = v;
    __syncthreads();
    for (int off = 1; off < 512; off <<= 1) {
        int t = (threadIdx.x >= off) ? sh[threadIdx.x - off] : 0;
        __syncthreads();
        sh[threadIdx.x] += t;
        __syncthreads();
    }
    if (threadIdx.x < NBLK) bsum[threadIdx.x] = sh[threadIdx.x] - v;
}

// add block offsets; init cursor; set row_start[N]; also dinv = rsqrt(cnt+1)
__global__ void scan3_kernel(int* __restrict__ row_start, const int* __restrict__ bsum,
                             int* __restrict__ cursor, const int* __restrict__ cnt,
                             float* __restrict__ dinv) {
    int i = blockIdx.x * 256 + threadIdx.x;
    if (i < NNODES) {
        int r = row_start[i] + bsum[blockIdx.x];
        row_start[i] = r;
        cursor[i] = r;
        dinv[i] = rsqrtf((float)cnt[i] + 1.0f);
    }
    if (i == 0) row_start[NNODES] = NEDGES;
}

__global__ void fill_kernel(const int* __restrict__ src, const int* __restrict__ dst,
                            int* __restrict__ cursor, int* __restrict__ csr_src) {
    int e = blockIdx.x * blockDim.x + threadIdx.x;
    if (e < NEDGES) {
        int p = atomicAdd(&cursor[dst[e]], 1);
        csr_src[p] = src[e];
    }
}

// ---------------- GCN layers ----------------

// th[i][f] = (in[i][:] @ W[:][f]) * dinv[i]
template<int FIN, int FOUT>
__global__ void transform_kernel(const float* __restrict__ in, const float* __restrict__ W,
                                 const float* __restrict__ dinv, float* __restrict__ th) {
    __shared__ float Ws[FIN * FOUT];
    for (int t = threadIdx.x; t < FIN * FOUT; t += blockDim.x) Ws[t] = W[t];
    __syncthreads();

    int idx = blockIdx.x * blockDim.x + threadIdx.x;
    if (idx >= NNODES * FOUT) return;
    int i = idx / FOUT;   // compile-time divisor -> magic multiply
    int f = idx % FOUT;

    const float* row = in + i * FIN;
    float sum = 0.f;
#pragma unroll
    for (int k = 0; k < FIN; ++k) sum += row[k] * Ws[k * FOUT + f];
    th[idx] = sum * dinv[i];
}

// out[i][f] = maybe_relu(dinv[i] * (th[i][f] + sum_nbr th[nbr][f]) + b[f])
// thread owns one float4 of one node's row
template<int FOUT, bool RELU>
__global__ void gather_kernel(const float* __restrict__ th, const int* __restrict__ row_start,
                              const int* __restrict__ csr_src, const float* __restrict__ dinv,
                              const float* __restrict__ b, float* __restrict__ out) {
    constexpr int NQ = FOUT / 4;   // 16 or 28
    int idx = blockIdx.x * blockDim.x + threadIdx.x;
    if (idx >= NNODES * NQ) return;
    int i = idx / NQ;
    int q = idx % NQ;

    const float4* t4 = (const float4*)th;
    float4 acc = t4[i * NQ + q];              // self-loop term
    int beg = row_start[i], end = row_start[i + 1];
    for (int k = beg; k < end; ++k) {
        int s = csr_src[k];
        float4 v = t4[s * NQ + q];
        acc.x += v.x; acc.y += v.y; acc.z += v.z; acc.w += v.w;
    }
    float di = dinv[i];
    float4 bb = ((const float4*)b)[q];
    float4 o;
    o.x = acc.x * di + bb.x;
    o.y = acc.y * di + bb.y;
    o.z = acc.z * di + bb.z;
    o.w = acc.w * di + bb.w;
    if (RELU) {
        o.x = fmaxf(o.x, 0.f); o.y = fmaxf(o.y, 0.f);
        o.z = fmaxf(o.z, 0.f); o.w = fmaxf(o.w, 0.f);
    }
    ((float4*)out)[i * NQ + q] = o;
}

extern "C" void kernel_launch(void* const* d_in, const int* in_sizes, int n_in,
                              void* d_out, int out_size, void* d_ws, size_t ws_size,
                              hipStream_t stream) {
    const float* x  = (const float*)d_in[0];
    const int*   ei = (const int*)d_in[1];
    const float* W1 = (const float*)d_in[2];
    const float* b1 = (const float*)d_in[3];
    const float* W2 = (const float*)d_in[4];
    const float* b2 = (const float*)d_in[5];
    const float* W3 = (const float*)d_in[6];
    const float* b3 = (const float*)d_in[7];

    const int* src = ei;            // edge_index[0]
    const int* dst = ei + NEDGES;   // edge_index[1]

    float* out = (float*)d_out;     // N*112; also reused as h2 scratch

    // workspace layout (16B-aligned chunks)
    char* w = (char*)d_ws;
    int*   cnt       = (int*)w;                    w += ((NNODES + 3) / 4) * 16;
    int*   row_start = (int*)w;                    w += ((NNODES + 1 + 3) / 4) * 16;
    int*   cursor    = (int*)w;                    w += ((NNODES + 3) / 4) * 16;
    int*   bsum      = (int*)w;                    w += 512 * 4;
    int*   csr_src   = (int*)w;                    w += (size_t)NEDGES * 4;
    float* dinv      = (float*)w;                  w += ((NNODES + 3) / 4) * 16;
    float* th        = (float*)w;                  w += (size_t)NNODES * 112 * 4;  // bufT
    float* h1        = (float*)w;                  w += (size_t)NNODES * 64 * 4;   // bufH
    // total ~84.9 MB

    const int B = 256;
    int gN    = (NNODES + B - 1) / B;          // 391
    int gE    = (NEDGES + B - 1) / B;
    int gN64  = (NNODES * 64 + B - 1) / B;
    int gN112 = (NNODES * 112 + B - 1) / B;
    int gG64  = (NNODES * 16 + B - 1) / B;     // gather F=64 (float4)
    int gG112 = (NNODES * 28 + B - 1) / B;     // gather F=112 (float4)

    // --- CSR build + normalization ---
    cnt_init_kernel<<<gN, B, 0, stream>>>(cnt);
    hist_kernel<<<gE, B, 0, stream>>>(dst, cnt);
    scan1_kernel<<<gN, 256, 0, stream>>>(cnt, row_start, bsum);
    scan2_kernel<<<1, 512, 0, stream>>>(bsum);
    scan3_kernel<<<gN, 256, 0, stream>>>(row_start, bsum, cursor, cnt, dinv);
    fill_kernel<<<gE, B, 0, stream>>>(src, dst, cursor, csr_src);

    // --- layer 1: x(8) -> 64, ReLU ---
    transform_kernel<8, 64><<<gN64, B, 0, stream>>>(x, W1, dinv, th);
    gather_kernel<64, true><<<gG64, B, 0, stream>>>(th, row_start, csr_src, dinv, b1, h1);

    // --- layer 2: 64 -> 64, ReLU (h2 lives in d_out) ---
    transform_kernel<64, 64><<<gN64, B, 0, stream>>>(h1, W2, dinv, th);
    gather_kernel<64, true><<<gG64, B, 0, stream>>>(th, row_start, csr_src, dinv, b2, out);

    // --- layer 3: 64 -> 112, no ReLU ---
    transform_kernel<64, 112><<<gN112, B, 0, stream>>>(out, W3, dinv, th);
    gather_kernel<112, false><<<gG112, B, 0, stream>>>(th, row_start, csr_src, dinv, b3, out);
}

// Round 3
// 1127.739 us; speedup vs baseline: 9.3329x; 1.1668x over previous
//
#include <hip/hip_runtime.h>

// GCN: N=100000 nodes, E=3200000 edges, dims 8 -> 64 -> 64 -> 112
//
// Algebraic form used here (N = D^-1/2 (A+I) D^-1/2 commutes with right-mult by W):
//   per layer: agg[i] = hs[i] + sum_{j->i} hs[j]          (hs already scaled by dinv)
//              t      = (dinv[i] * agg[i]) @ W + b
//              hs_out = relu(t) * dinv[i]   (inner layers; final layer stores t raw)
// Layer 1 aggregates the 8-dim input (L2-resident), layer 3 aggregates 64-dim h2
// before the 64->112 transform: aggregate on min(FIN,FOUT).

#define NNODES 100000
#define NEDGES 3200000
#define NBLK   ((NNODES + 255) / 256)   // 391 scan blocks

// ---------------- CSR build ----------------

__global__ void cnt_init_kernel(int* __restrict__ cnt) {
    int i = blockIdx.x * blockDim.x + threadIdx.x;
    if (i < NNODES) cnt[i] = 0;
}

__global__ void hist_kernel(const int* __restrict__ dst, int* __restrict__ cnt) {
    int e = blockIdx.x * blockDim.x + threadIdx.x;
    if (e < NEDGES) atomicAdd(&cnt[dst[e]], 1);
}

// per-block exclusive scan; block sums out
__global__ void scan1_kernel(const int* __restrict__ cnt, int* __restrict__ excl,
                             int* __restrict__ bsum) {
    __shared__ int sh[256];
    int i = blockIdx.x * 256 + threadIdx.x;
    int v = (i < NNODES) ? cnt[i] : 0;
    sh[threadIdx.x] = v;
    __syncthreads();
    for (int off = 1; off < 256; off <<= 1) {
        int t = (threadIdx.x >= off) ? sh[threadIdx.x - off] : 0;
        __syncthreads();
        sh[threadIdx.x] += t;
        __syncthreads();
    }
    if (i < NNODES) excl[i] = sh[threadIdx.x] - v;   // exclusive
    if (threadIdx.x == 255) bsum[blockIdx.x] = sh[255];
}

// single-block exclusive scan of the 391 block sums
__global__ void scan2_kernel(int* __restrict__ bsum) {
    __shared__ int sh[512];
    int v = (threadIdx.x < NBLK) ? bsum[threadIdx.x] : 0;
    sh[threadIdx.x] = v;
    __syncthreads();
    for (int off = 1; off < 512; off <<= 1) {
        int t = (threadIdx.x >= off) ? sh[threadIdx.x - off] : 0;
        __syncthreads();
        sh[threadIdx.x] += t;
        __syncthreads();
    }
    if (threadIdx.x < NBLK) bsum[threadIdx.x] = sh[threadIdx.x] - v;
}

// add block offsets; init cursor; set row_start[N]; dinv = rsqrt(cnt+1)
__global__ void scan3_kernel(int* __restrict__ row_start, const int* __restrict__ bsum,
                             int* __restrict__ cursor, const int* __restrict__ cnt,
                             float* __restrict__ dinv) {
    int i = blockIdx.x * 256 + threadIdx.x;
    if (i < NNODES) {
        int r = row_start[i] + bsum[blockIdx.x];
        row_start[i] = r;
        cursor[i] = r;
        dinv[i] = rsqrtf((float)cnt[i] + 1.0f);
    }
    if (i == 0) row_start[NNODES] = NEDGES;
}

__global__ void fill_kernel(const int* __restrict__ src, const int* __restrict__ dst,
                            int* __restrict__ cursor, int* __restrict__ csr_src) {
    int e = blockIdx.x * blockDim.x + threadIdx.x;
    if (e < NEDGES) {
        int p = atomicAdd(&cursor[dst[e]], 1);
        csr_src[p] = src[e];
    }
}

// ---------------- GCN layers ----------------

// xs[i][:] = x[i][:] * dinv[i]   (8 floats per node = 2 float4 per node)
__global__ void prescale_kernel(const float* __restrict__ x, const float* __restrict__ dinv,
                                float* __restrict__ xs) {
    int idx = blockIdx.x * blockDim.x + threadIdx.x;   // over N*2 float4s
    if (idx >= NNODES * 2) return;
    float di = dinv[idx >> 1];
    float4 v = ((const float4*)x)[idx];
    v.x *= di; v.y *= di; v.z *= di; v.w *= di;
    ((float4*)xs)[idx] = v;
}

// agg[i][:] = hs[i][:] + sum_{j in N(i)} hs[j][:]   (pure row-sum, thread owns a float4)
template<int F>
__global__ void gather_kernel(const float* __restrict__ hs, const int* __restrict__ row_start,
                              const int* __restrict__ csr_src, float* __restrict__ agg) {
    constexpr int NQ = F / 4;
    int idx = blockIdx.x * blockDim.x + threadIdx.x;
    if (idx >= NNODES * NQ) return;
    int i = idx / NQ;
    int q = idx % NQ;

    const float4* t4 = (const float4*)hs;
    float4 acc = t4[i * NQ + q];              // self-loop
    int beg = row_start[i], end = row_start[i + 1];
    for (int k = beg; k < end; ++k) {
        int s = csr_src[k];
        float4 v = t4[s * NQ + q];
        acc.x += v.x; acc.y += v.y; acc.z += v.z; acc.w += v.w;
    }
    ((float4*)agg)[i * NQ + q] = acc;
}

// out[i][f] = post( dinv[i] * (agg[i][:] @ W[:][f]) + b[f] )
// post: RELU -> relu; SCALE -> *dinv[i] (stored state for next layer's gather)
template<int FIN, int FOUT, bool RELU, bool SCALE>
__global__ void transform_kernel(const float* __restrict__ agg, const float* __restrict__ dinv,
                                 const float* __restrict__ W, const float* __restrict__ b,
                                 float* __restrict__ out) {
    __shared__ float Ws[FIN * FOUT];
    __shared__ float bs[FOUT];
    for (int t = threadIdx.x; t < FIN * FOUT; t += blockDim.x) Ws[t] = W[t];
    for (int t = threadIdx.x; t < FOUT; t += blockDim.x) bs[t] = b[t];
    __syncthreads();

    int idx = blockIdx.x * blockDim.x + threadIdx.x;
    if (idx >= NNODES * FOUT) return;
    int i = idx / FOUT;   // compile-time divisor -> magic multiply
    int f = idx % FOUT;

    const float* row = agg + i * FIN;
    float sum = 0.f;
#pragma unroll
    for (int k = 0; k < FIN; ++k) sum += row[k] * Ws[k * FOUT + f];

    float di = dinv[i];
    float v = sum * di + bs[f];
    if (RELU)  v = fmaxf(v, 0.f);
    if (SCALE) v *= di;
    out[idx] = v;
}

extern "C" void kernel_launch(void* const* d_in, const int* in_sizes, int n_in,
                              void* d_out, int out_size, void* d_ws, size_t ws_size,
                              hipStream_t stream) {
    const float* x  = (const float*)d_in[0];
    const int*   ei = (const int*)d_in[1];
    const float* W1 = (const float*)d_in[2];
    const float* b1 = (const float*)d_in[3];
    const float* W2 = (const float*)d_in[4];
    const float* b2 = (const float*)d_in[5];
    const float* W3 = (const float*)d_in[6];
    const float* b3 = (const float*)d_in[7];

    const int* src = ei;            // edge_index[0]
    const int* dst = ei + NEDGES;   // edge_index[1]

    float* out = (float*)d_out;     // N*112

    // workspace layout (16B-aligned chunks)
    char* w = (char*)d_ws;
    int*   cnt       = (int*)w;                    w += ((NNODES + 3) / 4) * 16;
    int*   row_start = (int*)w;                    w += ((NNODES + 1 + 3) / 4) * 16;
    int*   cursor    = (int*)w;                    w += ((NNODES + 3) / 4) * 16;
    int*   bsum      = (int*)w;                    w += 512 * 4;
    int*   csr_src   = (int*)w;                    w += (size_t)NEDGES * 4;
    float* dinv      = (float*)w;                  w += ((NNODES + 3) / 4) * 16;
    float* xs        = (float*)w;                  w += (size_t)NNODES * 8 * 4;
    float* aggX      = (float*)w;                  w += (size_t)NNODES * 8 * 4;
    float* bufH      = (float*)w;                  w += (size_t)NNODES * 64 * 4;   // hs
    float* bufG      = (float*)w;                  w += (size_t)NNODES * 64 * 4;   // agg
    // total ~72 MB

    const int B = 256;
    int gN    = (NNODES + B - 1) / B;              // 391
    int gE    = (NEDGES + B - 1) / B;
    int gN2   = (NNODES * 2  + B - 1) / B;
    int gN64  = (NNODES * 64 + B - 1) / B;
    int gN112 = (NNODES * 112 + B - 1) / B;
    int gG8   = (NNODES * 2  + B - 1) / B;         // gather F=8
    int gG64  = (NNODES * 16 + B - 1) / B;         // gather F=64

    // --- CSR build + normalization ---
    cnt_init_kernel<<<gN, B, 0, stream>>>(cnt);
    hist_kernel<<<gE, B, 0, stream>>>(dst, cnt);
    scan1_kernel<<<gN, 256, 0, stream>>>(cnt, row_start, bsum);
    scan2_kernel<<<1, 512, 0, stream>>>(bsum);
    scan3_kernel<<<gN, 256, 0, stream>>>(row_start, bsum, cursor, cnt, dinv);
    fill_kernel<<<gE, B, 0, stream>>>(src, dst, cursor, csr_src);

    // --- layer 1: aggregate x (8-dim), then 8->64, ReLU, scale ---
    prescale_kernel<<<gN2, B, 0, stream>>>(x, dinv, xs);
    gather_kernel<8><<<gG8, B, 0, stream>>>(xs, row_start, csr_src, aggX);
    transform_kernel<8, 64, true, true><<<gN64, B, 0, stream>>>(aggX, dinv, W1, b1, bufH);

    // --- layer 2: aggregate hs1 (64-dim), then 64->64, ReLU, scale ---
    gather_kernel<64><<<gG64, B, 0, stream>>>(bufH, row_start, csr_src, bufG);
    transform_kernel<64, 64, true, true><<<gN64, B, 0, stream>>>(bufG, dinv, W2, b2, bufH);

    // --- layer 3: aggregate hs2 (64-dim), then 64->112, no ReLU, no scale ---
    gather_kernel<64><<<gG64, B, 0, stream>>>(bufH, row_start, csr_src, bufG);
    transform_kernel<64, 112, false, false><<<gN112, B, 0, stream>>>(bufG, dinv, W3, b3, out);
}